// Round 17
// baseline (199.482 us; speedup 1.0000x reference)
//
#include <hip/hip_runtime.h>
#include <hip/hip_bf16.h>

typedef float f32x4 __attribute__((ext_vector_type(4)));
typedef float f32x16 __attribute__((ext_vector_type(16)));
typedef short s16x8 __attribute__((ext_vector_type(8)));
typedef short s16x4 __attribute__((ext_vector_type(4)));
typedef unsigned int u32x4 __attribute__((ext_vector_type(4)));

#define B_ 4
#define T_ 2048
#define C_ 1024
#define H_ 16
#define DH_ 64
#define M_ (B_*T_)      // 8192
#define N3_ (3*C_)      // 3072

static __device__ __forceinline__ short f2bf(float f) {
    __hip_bfloat16 h = __float2bfloat16(f);
    return *reinterpret_cast<short*>(&h);
}

// hardware packed f32x2 -> bf16x2 (lo in low half), RNE
static __device__ __forceinline__ unsigned pack2(float lo, float hi) {
    unsigned r;
    asm("v_cvt_pk_bf16_f32 %0, %1, %2" : "=v"(r) : "v"(lo), "v"(hi));
    return r;
}

// raw v_exp_f32: D = 2^S0 (scores bounded, pre-scaled to log2 domain)
static __device__ __forceinline__ float exp2_raw(float x) {
    float r;
    asm("v_exp_f32 %0, %1" : "=v"(r) : "v"(x));
    return r;
}

// async global->LDS, 16B per lane. LDS dest is wave-uniform base + lane*16.
static __device__ __forceinline__ void gload16(const void* g, void* l) {
    __builtin_amdgcn_global_load_lds(
        (const __attribute__((address_space(1))) void*)g,
        (__attribute__((address_space(3))) void*)l, 16, 0, 0);
}

// swizzled b128 fragment read from a linear [rows][64-short] LDS tile.
static __device__ __forceinline__ s16x8 lds_frag(const short* base, int row, int chunk) {
    return *(const s16x8*)&base[(row << 6) + ((chunk ^ (row & 7)) << 3)];
}

// ---------------- prep kernels ----------------

__global__ __launch_bounds__(256) void cast_f32_bf16(
    const float* __restrict__ in, short* __restrict__ out, int n8)
{
    int i = blockIdx.x * 256 + threadIdx.x;
    if (i >= n8) return;
    float4 a = *(const float4*)&in[i * 8];
    float4 b = *(const float4*)&in[i * 8 + 4];
    s16x8 o = { f2bf(a.x), f2bf(a.y), f2bf(a.z), f2bf(a.w),
                f2bf(b.x), f2bf(b.y), f2bf(b.z), f2bf(b.w) };
    *(s16x8*)&out[i * 8] = o;
}

// src [K][N] f32 row-major  ->  dst [N][K] bf16 row-major
__global__ __launch_bounds__(256) void transpose_cast(
    const float* __restrict__ src, short* __restrict__ dst, int K, int N)
{
    __shared__ short t[64][66];
    int tid = threadIdx.x;
    int n0 = blockIdx.x * 64, k0 = blockIdx.y * 64;
    #pragma unroll
    for (int p = 0; p < 4; ++p) {
        int cid = tid + p * 256;
        int r = cid >> 4, c4 = cid & 15;
        float4 v = *(const float4*)&src[(size_t)(k0 + r) * N + n0 + c4 * 4];
        t[r][c4 * 4 + 0] = f2bf(v.x);
        t[r][c4 * 4 + 1] = f2bf(v.y);
        t[r][c4 * 4 + 2] = f2bf(v.z);
        t[r][c4 * 4 + 3] = f2bf(v.w);
    }
    __syncthreads();
    #pragma unroll
    for (int p = 0; p < 4; ++p) {
        int cid = tid + p * 256;
        int r = cid >> 4, c4 = cid & 15;
        s16x4 ov;
        #pragma unroll
        for (int j = 0; j < 4; ++j) ov[j] = t[c4 * 4 + j][r];
        *(s16x4*)&dst[(size_t)(n0 + r) * K + k0 + c4 * 4] = ov;
    }
}

// ---------------- GEMM: C[M][N] = A[M][1024] * Bt[N][1024]^T (+bias) ----------------
// Counted-vmcnt double-buffer: stage tile k+1 during compute of tile k; raw
// s_barrier + per-wave vmcnt(8) -- no vmcnt(0) drain in the main loop.
// MODE 1: q pre-scaled by 1/sqrt(dh)*log2(e); v stored sigma-permuted (g bit-swap)

template<int MODE>
__global__ __launch_bounds__(256) void gemm_bt(
    const short* __restrict__ A, const short* __restrict__ Bt,
    const float* __restrict__ bias, float* __restrict__ out,
    short* __restrict__ qout, short* __restrict__ kout, short* __restrict__ vout)
{
    const int K = 1024;
    __shared__ short As[2][128 * 64];
    __shared__ short Bs[2][128 * 64];
    int tid = threadIdx.x;
    int lane = tid & 63, w = tid >> 6;
    int d = lane & 15, g = lane >> 4;
    int wm = w >> 1, wn = w & 1;

    // XCD-aware bijective swizzle (grid sizes divisible by 8)
    int gx = gridDim.x;
    int lid = blockIdx.y * gx + blockIdx.x;
    int chunk = (gx * gridDim.y) >> 3;
    int sl = (lid & 7) * chunk + (lid >> 3);
    int m0 = (sl / gx) * 128, n0 = (sl % gx) * 128;

    f32x4 acc[4][4];
    #pragma unroll
    for (int i = 0; i < 4; ++i)
        #pragma unroll
        for (int j = 0; j < 4; ++j) acc[i][j] = (f32x4){0.f, 0.f, 0.f, 0.f};

    // staging geometry (loop-invariant)
    int r_ = tid >> 3, c8_ = tid & 7;
    int co_ = (c8_ ^ (r_ & 7)) << 3;

    #define GSTAGE(buf, kt) do { \
        _Pragma("unroll") \
        for (int p = 0; p < 4; ++p) { \
            int rr = p * 32 + r_; \
            int dofs = (p * 256 + (tid & ~63)) * 8; \
            gload16(&A[(size_t)(m0 + rr) * K + (kt) + co_], &As[buf][dofs]); \
            gload16(&Bt[(size_t)(n0 + rr) * K + (kt) + co_], &Bs[buf][dofs]); \
        } \
    } while (0)

    GSTAGE(0, 0);
    int cur = 0;

    #pragma unroll 1
    for (int kt = 0; kt < K; kt += 64) {
        if (kt + 64 < K) {
            GSTAGE(cur ^ 1, kt + 64);
            asm volatile("s_waitcnt vmcnt(8)" ::: "memory");  // tile kt ready; kt+64 in flight
        } else {
            asm volatile("s_waitcnt vmcnt(0)" ::: "memory");
        }
        __builtin_amdgcn_s_barrier();

        const short* Ab = As[cur];
        const short* Bb = Bs[cur];
        #pragma unroll
        for (int ks = 0; ks < 2; ++ks) {
            s16x8 af[4], bf[4];
            #pragma unroll
            for (int i = 0; i < 4; ++i) {
                af[i] = lds_frag(Ab, wm * 64 + i * 16 + d, ks * 4 + g);
                bf[i] = lds_frag(Bb, wn * 64 + i * 16 + d, ks * 4 + g);
            }
            #pragma unroll
            for (int mi = 0; mi < 4; ++mi)
                #pragma unroll
                for (int ni = 0; ni < 4; ++ni)
                    acc[mi][ni] = __builtin_amdgcn_mfma_f32_16x16x32_bf16(
                        af[mi], bf[ni], acc[mi][ni], 0, 0, 0);
        }

        __builtin_amdgcn_s_barrier();
        cur ^= 1;
    }
    #undef GSTAGE

    #pragma unroll
    for (int mi = 0; mi < 4; ++mi)
        #pragma unroll
        for (int ni = 0; ni < 4; ++ni) {
            int gn = n0 + wn * 64 + ni * 16 + d;
            float bv = bias[gn];
            int gm0 = m0 + wm * 64 + mi * 16 + g * 4;
            if (MODE == 0) {
                #pragma unroll
                for (int r = 0; r < 4; ++r)
                    out[(size_t)(gm0 + r) * 1024 + gn] = acc[mi][ni][r] + bv;
            } else {
                int which = gn >> 10, cc = gn & 1023;
                int h = cc >> 6, dh = cc & 63;
                int b = gm0 >> 11;
                if (which == 2) {
                    // sigma-permute t within its 16-group: swap bits of g
                    int g2 = ((g & 1) << 1) | (g >> 1);
                    int t0v = (gm0 & 2047) - g * 4 + g2 * 4;
                    s16x4 pv;
                    #pragma unroll
                    for (int r = 0; r < 4; ++r) pv[r] = f2bf(acc[mi][ni][r] + bv);
                    *(s16x4*)&vout[((size_t)(b * 16 + h) * 64 + dh) * 2048 + t0v] = pv;
                } else if (which == 1) {
                    int t0 = gm0 & 2047;
                    #pragma unroll
                    for (int r = 0; r < 4; ++r)
                        kout[((size_t)(b * 16 + h) * 2048 + (t0 + r)) * 64 + dh] =
                            f2bf(acc[mi][ni][r] + bv);
                } else {
                    int t0 = gm0 & 2047;
                    const float SC2 = 0.125f * 1.44269504089f;  // 1/sqrt(64)*log2(e)
                    #pragma unroll
                    for (int r = 0; r < 4; ++r)
                        qout[((size_t)(b * 16 + h) * 2048 + (t0 + r)) * 64 + dh] =
                            f2bf((acc[mi][ni][r] + bv) * SC2);
                }
            }
        }
}

// ---------------- flash attention ----------------
// r16 best structure + ONE change: commutative K-tile order with per-block
// start offset t0 = bid % nt. The no-max softmax makes tile order commutative
// (l, oA, oB are pure sums; masking is per-tile) -- co-resident blocks now run
// phase-decorrelated, so one block's staging stall overlaps another's compute.

__global__ __launch_bounds__(256, 4) void attn_fwd(
    const short* __restrict__ q, const short* __restrict__ kk,
    const short* __restrict__ vt, short* __restrict__ y)
{
    __shared__ short Ks[2][64 * 64];
    __shared__ short Vs[2][64 * 64];
    int tid = threadIdx.x, w = tid >> 6;
    int lane = tid & 63;
    int q5 = lane & 31, h5 = lane >> 5;
    int bid = blockIdx.x;
    int idx = bid >> 3;
    int qt = 15 - (idx >> 3);
    int bh = ((idx & 7) << 3) | (bid & 7);
    int b = bh >> 4, hh = bh & 15;
    const size_t hb = (size_t)bh * 2048 * 64;
    int nt = 2 * qt + 2;                 // # of 64-wide K tiles (>=2)
    int qrow = qt * 128 + w * 32;
    int qg = qrow + q5;
    int t0 = bid % nt;                   // phase-stagger start tile

    s16x8 qf[4];
    #pragma unroll
    for (int s = 0; s < 4; ++s)
        qf[s] = *(const s16x8*)&q[hb + (size_t)qg * 64 + 16 * s + 8 * h5];

    f32x16 oA, oB;
    #pragma unroll
    for (int i = 0; i < 16; ++i) { oA[i] = 0.f; oB[i] = 0.f; }
    float l = 0.f;

    #define STAGE(buf, kt2) do { \
        _Pragma("unroll") \
        for (int p = 0; p < 2; ++p) { \
            int cid = p * 256 + tid; \
            int r__ = cid >> 3, c8__ = cid & 7; \
            int co__ = (c8__ ^ (r__ & 7)) << 3; \
            int dofs__ = (p * 256 + (tid & ~63)) * 8; \
            gload16(&kk[hb + (size_t)((kt2) * 64 + r__) * 64 + co__], &Ks[buf][dofs__]); \
            gload16(&vt[hb + (size_t)r__ * 2048 + (kt2) * 64 + co__], &Vs[buf][dofs__]); \
        } \
    } while (0)

    STAGE(0, t0);
    int cur = 0;

    #pragma unroll 1
    for (int i = 0; i < nt; ++i) {
        int t = t0 + i; if (t >= nt) t -= nt;
        if (i + 1 < nt) {
            int tn = t + 1; if (tn >= nt) tn -= nt;
            STAGE(cur ^ 1, tn);
            asm volatile("s_waitcnt vmcnt(4)" ::: "memory");  // tile t ready; next in flight
        } else {
            asm volatile("s_waitcnt vmcnt(0)" ::: "memory");
        }
        __builtin_amdgcn_s_barrier();

        if (t * 64 <= qrow + 31) {
            const short* Kb = Ks[cur];
            const short* Vb = Vs[cur];

            f32x16 sA, sB;
            #pragma unroll
            for (int i2 = 0; i2 < 16; ++i2) { sA[i2] = 0.f; sB[i2] = 0.f; }
            #pragma unroll
            for (int s = 0; s < 4; ++s) {
                sA = __builtin_amdgcn_mfma_f32_32x32x16_bf16(
                    lds_frag(Kb, q5, 2 * s + h5), qf[s], sA, 0, 0, 0);
                sB = __builtin_amdgcn_mfma_f32_32x32x16_bf16(
                    lds_frag(Kb, 32 + q5, 2 * s + h5), qf[s], sB, 0, 0, 0);
            }

            float eA[16], eB[16];
            float S = 0.f;
            if (t * 64 + 63 > qrow) {
                #pragma unroll
                for (int rg = 0; rg < 16; ++rg) {
                    int kg = t * 64 + (rg & 3) + 8 * (rg >> 2) + 4 * h5;
                    float a = exp2_raw(sA[rg]); if (kg > qg) a = 0.f;
                    float c = exp2_raw(sB[rg]); if (kg + 32 > qg) c = 0.f;
                    eA[rg] = a; eB[rg] = c; S += a + c;
                }
            } else {
                #pragma unroll
                for (int rg = 0; rg < 16; ++rg) {
                    float a = exp2_raw(sA[rg]);
                    float c = exp2_raw(sB[rg]);
                    eA[rg] = a; eB[rg] = c; S += a + c;
                }
            }
            l += S;

            unsigned wdA[8], wdB[8];
            #pragma unroll
            for (int m = 0; m < 4; ++m) {
                wdA[2 * m]     = pack2(eA[4 * m],     eA[4 * m + 1]);
                wdA[2 * m + 1] = pack2(eA[4 * m + 2], eA[4 * m + 3]);
                wdB[2 * m]     = pack2(eB[4 * m],     eB[4 * m + 1]);
                wdB[2 * m + 1] = pack2(eB[4 * m + 2], eB[4 * m + 3]);
            }

            #pragma unroll
            for (int kc = 0; kc < 4; ++kc) {
                const unsigned* wsrc = (kc < 2) ? wdA : wdB;
                int o4 = (kc & 1) << 2;
                u32x4 pw = {wsrc[o4], wsrc[o4 + 1], wsrc[o4 + 2], wsrc[o4 + 3]};
                s16x8 pb = __builtin_bit_cast(s16x8, pw);
                oA = __builtin_amdgcn_mfma_f32_32x32x16_bf16(
                    lds_frag(Vb, q5, 2 * kc + h5), pb, oA, 0, 0, 0);
                oB = __builtin_amdgcn_mfma_f32_32x32x16_bf16(
                    lds_frag(Vb, 32 + q5, 2 * kc + h5), pb, oB, 0, 0, 0);
            }
        }

        __builtin_amdgcn_s_barrier();
        cur ^= 1;
    }

    l += __shfl_xor(l, 32);
    float rl = 1.0f / l;

    short* yp = &y[(size_t)(b * 2048 + qg) * 1024 + hh * 64];
    #pragma unroll
    for (int m = 0; m < 4; ++m) {
        s16x4 v0, v1;
        #pragma unroll
        for (int i = 0; i < 4; ++i) {
            v0[i] = f2bf(oA[4 * m + i] * rl);
            v1[i] = f2bf(oB[4 * m + i] * rl);
        }
        *(s16x4*)&yp[8 * m + 4 * h5] = v0;
        *(s16x4*)&yp[32 + 8 * m + 4 * h5] = v1;
    }
    #undef STAGE
}

// ---------------- launch ----------------

extern "C" void kernel_launch(void* const* d_in, const int* in_sizes, int n_in,
                              void* d_out, int out_size, void* d_ws, size_t ws_size,
                              hipStream_t stream)
{
    const float* x    = (const float*)d_in[0];
    const float* Wqkv = (const float*)d_in[1];
    const float* bqkv = (const float*)d_in[2];
    const float* Wout = (const float*)d_in[3];
    const float* bout = (const float*)d_in[4];
    float* out = (float*)d_out;

    char* ws = (char*)d_ws;
    short* xbf   = (short*)ws;  ws += (size_t)M_ * C_ * 2;
    short* wqkvT = (short*)ws;  ws += (size_t)N3_ * C_ * 2;
    short* woutT = (short*)ws;  ws += (size_t)C_ * C_ * 2;
    short* qb    = (short*)ws;  ws += (size_t)M_ * C_ * 2;
    short* kb    = (short*)ws;  ws += (size_t)M_ * C_ * 2;
    short* vtb   = (short*)ws;  ws += (size_t)M_ * C_ * 2;   // V^T, sigma-permuted
    short* yb    = (short*)ws;  ws += (size_t)M_ * C_ * 2;

    cast_f32_bf16<<<(M_ * C_ / 8 + 255) / 256, 256, 0, stream>>>(x, xbf, M_ * C_ / 8);
    transpose_cast<<<dim3(N3_ / 64, C_ / 64), 256, 0, stream>>>(Wqkv, wqkvT, C_, N3_);
    transpose_cast<<<dim3(C_ / 64, C_ / 64), 256, 0, stream>>>(Wout, woutT, C_, C_);

    gemm_bt<1><<<dim3(N3_ / 128, M_ / 128), 256, 0, stream>>>(
        xbf, wqkvT, bqkv, nullptr, qb, kb, vtb);

    attn_fwd<<<dim3((T_ / 128) * B_ * H_), 256, 0, stream>>>(qb, kb, vtb, yb);

    gemm_bt<0><<<dim3(C_ / 128, M_ / 128), 256, 0, stream>>>(
        yb, woutT, bout, out, nullptr, nullptr, nullptr);
}

// Round 18
// 174.012 us; speedup vs baseline: 1.1464x; 1.1464x over previous
//
#include <hip/hip_runtime.h>
#include <hip/hip_bf16.h>

typedef float f32x4 __attribute__((ext_vector_type(4)));
typedef float f32x16 __attribute__((ext_vector_type(16)));
typedef short s16x8 __attribute__((ext_vector_type(8)));
typedef short s16x4 __attribute__((ext_vector_type(4)));
typedef unsigned int u32x4 __attribute__((ext_vector_type(4)));

#define B_ 4
#define T_ 2048
#define C_ 1024
#define H_ 16
#define DH_ 64
#define M_ (B_*T_)      // 8192
#define N3_ (3*C_)      // 3072

static __device__ __forceinline__ short f2bf(float f) {
    __hip_bfloat16 h = __float2bfloat16(f);
    return *reinterpret_cast<short*>(&h);
}

// hardware packed f32x2 -> bf16x2 (lo in low half), RNE
static __device__ __forceinline__ unsigned pack2(float lo, float hi) {
    unsigned r;
    asm("v_cvt_pk_bf16_f32 %0, %1, %2" : "=v"(r) : "v"(lo), "v"(hi));
    return r;
}

// raw v_exp_f32: D = 2^S0 (scores bounded, pre-scaled to log2 domain)
static __device__ __forceinline__ float exp2_raw(float x) {
    float r;
    asm("v_exp_f32 %0, %1" : "=v"(r) : "v"(x));
    return r;
}

// async global->LDS, 16B per lane. LDS dest is wave-uniform base + lane*16.
static __device__ __forceinline__ void gload16(const void* g, void* l) {
    __builtin_amdgcn_global_load_lds(
        (const __attribute__((address_space(1))) void*)g,
        (__attribute__((address_space(3))) void*)l, 16, 0, 0);
}

// swizzled b128 fragment read from a linear [rows][64-short] LDS tile.
static __device__ __forceinline__ s16x8 lds_frag(const short* base, int row, int chunk) {
    return *(const s16x8*)&base[(row << 6) + ((chunk ^ (row & 7)) << 3)];
}

// ---------------- prep kernels ----------------

__global__ __launch_bounds__(256) void cast_f32_bf16(
    const float* __restrict__ in, short* __restrict__ out, int n8)
{
    int i = blockIdx.x * 256 + threadIdx.x;
    if (i >= n8) return;
    float4 a = *(const float4*)&in[i * 8];
    float4 b = *(const float4*)&in[i * 8 + 4];
    s16x8 o = { f2bf(a.x), f2bf(a.y), f2bf(a.z), f2bf(a.w),
                f2bf(b.x), f2bf(b.y), f2bf(b.z), f2bf(b.w) };
    *(s16x8*)&out[i * 8] = o;
}

// src [K][N] f32 row-major  ->  dst [N][K] bf16 row-major
__global__ __launch_bounds__(256) void transpose_cast(
    const float* __restrict__ src, short* __restrict__ dst, int K, int N)
{
    __shared__ short t[64][66];
    int tid = threadIdx.x;
    int n0 = blockIdx.x * 64, k0 = blockIdx.y * 64;
    #pragma unroll
    for (int p = 0; p < 4; ++p) {
        int cid = tid + p * 256;
        int r = cid >> 4, c4 = cid & 15;
        float4 v = *(const float4*)&src[(size_t)(k0 + r) * N + n0 + c4 * 4];
        t[r][c4 * 4 + 0] = f2bf(v.x);
        t[r][c4 * 4 + 1] = f2bf(v.y);
        t[r][c4 * 4 + 2] = f2bf(v.z);
        t[r][c4 * 4 + 3] = f2bf(v.w);
    }
    __syncthreads();
    #pragma unroll
    for (int p = 0; p < 4; ++p) {
        int cid = tid + p * 256;
        int r = cid >> 4, c4 = cid & 15;
        s16x4 ov;
        #pragma unroll
        for (int j = 0; j < 4; ++j) ov[j] = t[c4 * 4 + j][r];
        *(s16x4*)&dst[(size_t)(n0 + r) * K + k0 + c4 * 4] = ov;
    }
}

// ---------------- GEMM: C[M][N] = A[M][1024] * Bt[N][1024]^T (+bias) ----------------
// Counted-vmcnt double-buffer (r16, verified): stage tile k+1 during compute of
// tile k; raw s_barrier + per-wave vmcnt(8).
// MODE 1: q pre-scaled by 1/sqrt(dh)*log2(e); v stored sigma-permuted (g bit-swap)

template<int MODE>
__global__ __launch_bounds__(256) void gemm_bt(
    const short* __restrict__ A, const short* __restrict__ Bt,
    const float* __restrict__ bias, float* __restrict__ out,
    short* __restrict__ qout, short* __restrict__ kout, short* __restrict__ vout)
{
    const int K = 1024;
    __shared__ short As[2][128 * 64];
    __shared__ short Bs[2][128 * 64];
    int tid = threadIdx.x;
    int lane = tid & 63, w = tid >> 6;
    int d = lane & 15, g = lane >> 4;
    int wm = w >> 1, wn = w & 1;

    // XCD-aware bijective swizzle (grid sizes divisible by 8)
    int gx = gridDim.x;
    int lid = blockIdx.y * gx + blockIdx.x;
    int chunk = (gx * gridDim.y) >> 3;
    int sl = (lid & 7) * chunk + (lid >> 3);
    int m0 = (sl / gx) * 128, n0 = (sl % gx) * 128;

    f32x4 acc[4][4];
    #pragma unroll
    for (int i = 0; i < 4; ++i)
        #pragma unroll
        for (int j = 0; j < 4; ++j) acc[i][j] = (f32x4){0.f, 0.f, 0.f, 0.f};

    // staging geometry (loop-invariant)
    int r_ = tid >> 3, c8_ = tid & 7;
    int co_ = (c8_ ^ (r_ & 7)) << 3;

    #define GSTAGE(buf, kt) do { \
        _Pragma("unroll") \
        for (int p = 0; p < 4; ++p) { \
            int rr = p * 32 + r_; \
            int dofs = (p * 256 + (tid & ~63)) * 8; \
            gload16(&A[(size_t)(m0 + rr) * K + (kt) + co_], &As[buf][dofs]); \
            gload16(&Bt[(size_t)(n0 + rr) * K + (kt) + co_], &Bs[buf][dofs]); \
        } \
    } while (0)

    GSTAGE(0, 0);
    int cur = 0;

    #pragma unroll 1
    for (int kt = 0; kt < K; kt += 64) {
        if (kt + 64 < K) {
            GSTAGE(cur ^ 1, kt + 64);
            asm volatile("s_waitcnt vmcnt(8)" ::: "memory");  // tile kt ready; kt+64 in flight
        } else {
            asm volatile("s_waitcnt vmcnt(0)" ::: "memory");
        }
        __builtin_amdgcn_s_barrier();

        const short* Ab = As[cur];
        const short* Bb = Bs[cur];
        #pragma unroll
        for (int ks = 0; ks < 2; ++ks) {
            s16x8 af[4], bf[4];
            #pragma unroll
            for (int i = 0; i < 4; ++i) {
                af[i] = lds_frag(Ab, wm * 64 + i * 16 + d, ks * 4 + g);
                bf[i] = lds_frag(Bb, wn * 64 + i * 16 + d, ks * 4 + g);
            }
            #pragma unroll
            for (int mi = 0; mi < 4; ++mi)
                #pragma unroll
                for (int ni = 0; ni < 4; ++ni)
                    acc[mi][ni] = __builtin_amdgcn_mfma_f32_16x16x32_bf16(
                        af[mi], bf[ni], acc[mi][ni], 0, 0, 0);
        }

        __builtin_amdgcn_s_barrier();
        cur ^= 1;
    }
    #undef GSTAGE

    #pragma unroll
    for (int mi = 0; mi < 4; ++mi)
        #pragma unroll
        for (int ni = 0; ni < 4; ++ni) {
            int gn = n0 + wn * 64 + ni * 16 + d;
            float bv = bias[gn];
            int gm0 = m0 + wm * 64 + mi * 16 + g * 4;
            if (MODE == 0) {
                #pragma unroll
                for (int r = 0; r < 4; ++r)
                    out[(size_t)(gm0 + r) * 1024 + gn] = acc[mi][ni][r] + bv;
            } else {
                int which = gn >> 10, cc = gn & 1023;
                int h = cc >> 6, dh = cc & 63;
                int b = gm0 >> 11;
                if (which == 2) {
                    // sigma-permute t within its 16-group: swap bits of g
                    int g2 = ((g & 1) << 1) | (g >> 1);
                    int t0v = (gm0 & 2047) - g * 4 + g2 * 4;
                    s16x4 pv;
                    #pragma unroll
                    for (int r = 0; r < 4; ++r) pv[r] = f2bf(acc[mi][ni][r] + bv);
                    *(s16x4*)&vout[((size_t)(b * 16 + h) * 64 + dh) * 2048 + t0v] = pv;
                } else if (which == 1) {
                    int t0 = gm0 & 2047;
                    #pragma unroll
                    for (int r = 0; r < 4; ++r)
                        kout[((size_t)(b * 16 + h) * 2048 + (t0 + r)) * 64 + dh] =
                            f2bf(acc[mi][ni][r] + bv);
                } else {
                    int t0 = gm0 & 2047;
                    const float SC2 = 0.125f * 1.44269504089f;  // 1/sqrt(64)*log2(e)
                    #pragma unroll
                    for (int r = 0; r < 4; ++r)
                        qout[((size_t)(b * 16 + h) * 2048 + (t0 + r)) * 64 + dh] =
                            f2bf((acc[mi][ni][r] + bv) * SC2);
                }
            }
        }
}

// ---------------- flash attention ----------------
// Paired-qt blocks, CONCURRENT: 512 blocks x 8 waves. Waves 0-3 own q-tile
// A (qt=15-pi), waves 4-7 own q-tile B (qt=pi); both consume ONE staged K/V
// tile per step, ascending t from 0 (L2 phase-aligned like r16). Every block
// = exactly 34 q-tile-iters of compute; co-resident {bid, bid+256} have the
// same pi -> equal work, zero tail. Staging volume -26% vs r16.

__global__ __launch_bounds__(512, 4) void attn_fwd(
    const short* __restrict__ q, const short* __restrict__ kk,
    const short* __restrict__ vt, short* __restrict__ y)
{
    __shared__ short Ks[2][64 * 64];
    __shared__ short Vs[2][64 * 64];
    int tid = threadIdx.x, w = tid >> 6;       // w: 0..7
    int lane = tid & 63;
    int q5 = lane & 31, h5 = lane >> 5;
    int bid = blockIdx.x;
    int stripe = bid & 7;                      // XCD
    int pi = (bid >> 3) & 7;                   // pair index
    int hi = bid >> 6;                         // 0..7
    int head = hi * 8 + stripe;                // 64 heads, stripe-local per XCD
    int b = head >> 4, hh = head & 15;
    const size_t hb = (size_t)head * 2048 * 64;
    int qt = (w >> 2) ? pi : (15 - pi);        // group A: 15-pi, group B: pi
    int wl = w & 3;
    int nt = 2 * (15 - pi) + 2;                // loop bound = group A's tiles
    int qrow = qt * 128 + wl * 32;
    int qg = qrow + q5;

    // staging geometry: 512 threads x 16B = one 64x64 bf16 tile per operand
    int r_ = tid >> 3, c8_ = tid & 7;
    int co_ = (c8_ ^ (r_ & 7)) << 3;
    int dofs_ = (tid & ~63) * 8;

    #define STAGE(buf, kt2) do { \
        gload16(&kk[hb + (size_t)((kt2) * 64 + r_) * 64 + co_], &Ks[buf][dofs_]); \
        gload16(&vt[hb + (size_t)r_ * 2048 + (kt2) * 64 + co_], &Vs[buf][dofs_]); \
    } while (0)

    s16x8 qf[4];
    #pragma unroll
    for (int s = 0; s < 4; ++s)
        qf[s] = *(const s16x8*)&q[hb + (size_t)qg * 64 + 16 * s + 8 * h5];

    f32x16 oA, oB;
    #pragma unroll
    for (int i = 0; i < 16; ++i) { oA[i] = 0.f; oB[i] = 0.f; }
    float l = 0.f;

    STAGE(0, 0);
    int cur = 0;

    #pragma unroll 1
    for (int t = 0; t < nt; ++t) {
        if (t + 1 < nt) {
            STAGE(cur ^ 1, t + 1);
            asm volatile("s_waitcnt vmcnt(2)" ::: "memory");  // tile t ready; t+1 in flight
        } else {
            asm volatile("s_waitcnt vmcnt(0)" ::: "memory");
        }
        __builtin_amdgcn_s_barrier();

        if (t * 64 <= qrow + 31) {             // wave-uniform: group still active
            const short* Kb = Ks[cur];
            const short* Vb = Vs[cur];

            f32x16 sA, sB;
            #pragma unroll
            for (int i2 = 0; i2 < 16; ++i2) { sA[i2] = 0.f; sB[i2] = 0.f; }
            #pragma unroll
            for (int s = 0; s < 4; ++s) {
                sA = __builtin_amdgcn_mfma_f32_32x32x16_bf16(
                    lds_frag(Kb, q5, 2 * s + h5), qf[s], sA, 0, 0, 0);
                sB = __builtin_amdgcn_mfma_f32_32x32x16_bf16(
                    lds_frag(Kb, 32 + q5, 2 * s + h5), qf[s], sB, 0, 0, 0);
            }

            float eA[16], eB[16];
            float S = 0.f;
            if (t * 64 + 63 > qrow) {
                #pragma unroll
                for (int rg = 0; rg < 16; ++rg) {
                    int kg = t * 64 + (rg & 3) + 8 * (rg >> 2) + 4 * h5;
                    float a = exp2_raw(sA[rg]); if (kg > qg) a = 0.f;
                    float c = exp2_raw(sB[rg]); if (kg + 32 > qg) c = 0.f;
                    eA[rg] = a; eB[rg] = c; S += a + c;
                }
            } else {
                #pragma unroll
                for (int rg = 0; rg < 16; ++rg) {
                    float a = exp2_raw(sA[rg]);
                    float c = exp2_raw(sB[rg]);
                    eA[rg] = a; eB[rg] = c; S += a + c;
                }
            }
            l += S;

            unsigned wdA[8], wdB[8];
            #pragma unroll
            for (int m = 0; m < 4; ++m) {
                wdA[2 * m]     = pack2(eA[4 * m],     eA[4 * m + 1]);
                wdA[2 * m + 1] = pack2(eA[4 * m + 2], eA[4 * m + 3]);
                wdB[2 * m]     = pack2(eB[4 * m],     eB[4 * m + 1]);
                wdB[2 * m + 1] = pack2(eB[4 * m + 2], eB[4 * m + 3]);
            }

            #pragma unroll
            for (int kc = 0; kc < 4; ++kc) {
                const unsigned* wsrc = (kc < 2) ? wdA : wdB;
                int o4 = (kc & 1) << 2;
                u32x4 pw = {wsrc[o4], wsrc[o4 + 1], wsrc[o4 + 2], wsrc[o4 + 3]};
                s16x8 pb = __builtin_bit_cast(s16x8, pw);
                oA = __builtin_amdgcn_mfma_f32_32x32x16_bf16(
                    lds_frag(Vb, q5, 2 * kc + h5), pb, oA, 0, 0, 0);
                oB = __builtin_amdgcn_mfma_f32_32x32x16_bf16(
                    lds_frag(Vb, 32 + q5, 2 * kc + h5), pb, oB, 0, 0, 0);
            }
        }

        __builtin_amdgcn_s_barrier();
        cur ^= 1;
    }

    l += __shfl_xor(l, 32);
    float rl = 1.0f / l;

    short* yp = &y[(size_t)(b * 2048 + qg) * 1024 + hh * 64];
    #pragma unroll
    for (int m = 0; m < 4; ++m) {
        s16x4 v0, v1;
        #pragma unroll
        for (int i = 0; i < 4; ++i) {
            v0[i] = f2bf(oA[4 * m + i] * rl);
            v1[i] = f2bf(oB[4 * m + i] * rl);
        }
        *(s16x4*)&yp[8 * m + 4 * h5] = v0;
        *(s16x4*)&yp[32 + 8 * m + 4 * h5] = v1;
    }
    #undef STAGE
}

// ---------------- launch ----------------

extern "C" void kernel_launch(void* const* d_in, const int* in_sizes, int n_in,
                              void* d_out, int out_size, void* d_ws, size_t ws_size,
                              hipStream_t stream)
{
    const float* x    = (const float*)d_in[0];
    const float* Wqkv = (const float*)d_in[1];
    const float* bqkv = (const float*)d_in[2];
    const float* Wout = (const float*)d_in[3];
    const float* bout = (const float*)d_in[4];
    float* out = (float*)d_out;

    char* ws = (char*)d_ws;
    short* xbf   = (short*)ws;  ws += (size_t)M_ * C_ * 2;
    short* wqkvT = (short*)ws;  ws += (size_t)N3_ * C_ * 2;
    short* woutT = (short*)ws;  ws += (size_t)C_ * C_ * 2;
    short* qb    = (short*)ws;  ws += (size_t)M_ * C_ * 2;
    short* kb    = (short*)ws;  ws += (size_t)M_ * C_ * 2;
    short* vtb   = (short*)ws;  ws += (size_t)M_ * C_ * 2;   // V^T, sigma-permuted
    short* yb    = (short*)ws;  ws += (size_t)M_ * C_ * 2;

    cast_f32_bf16<<<(M_ * C_ / 8 + 255) / 256, 256, 0, stream>>>(x, xbf, M_ * C_ / 8);
    transpose_cast<<<dim3(N3_ / 64, C_ / 64), 256, 0, stream>>>(Wqkv, wqkvT, C_, N3_);
    transpose_cast<<<dim3(C_ / 64, C_ / 64), 256, 0, stream>>>(Wout, woutT, C_, C_);

    gemm_bt<1><<<dim3(N3_ / 128, M_ / 128), 256, 0, stream>>>(
        xbf, wqkvT, bqkv, nullptr, qb, kb, vtb);

    attn_fwd<<<dim3(512), 512, 0, stream>>>(qb, kb, vtb, yb);

    gemm_bt<0><<<dim3(C_ / 128, M_ / 128), 256, 0, stream>>>(
        yb, woutT, bout, out, nullptr, nullptr, nullptr);
}

// Round 19
// 171.517 us; speedup vs baseline: 1.1630x; 1.0145x over previous
//
#include <hip/hip_runtime.h>
#include <hip/hip_bf16.h>

typedef float f32x4 __attribute__((ext_vector_type(4)));
typedef float f32x16 __attribute__((ext_vector_type(16)));
typedef short s16x8 __attribute__((ext_vector_type(8)));
typedef short s16x4 __attribute__((ext_vector_type(4)));
typedef unsigned int u32x4 __attribute__((ext_vector_type(4)));

#define B_ 4
#define T_ 2048
#define C_ 1024
#define H_ 16
#define DH_ 64
#define M_ (B_*T_)      // 8192
#define N3_ (3*C_)      // 3072

static __device__ __forceinline__ short f2bf(float f) {
    __hip_bfloat16 h = __float2bfloat16(f);
    return *reinterpret_cast<short*>(&h);
}

// hardware packed f32x2 -> bf16x2 (lo in low half), RNE
static __device__ __forceinline__ unsigned pack2(float lo, float hi) {
    unsigned r;
    asm("v_cvt_pk_bf16_f32 %0, %1, %2" : "=v"(r) : "v"(lo), "v"(hi));
    return r;
}

// raw v_exp_f32: D = 2^S0 (scores bounded, pre-scaled to log2 domain)
static __device__ __forceinline__ float exp2_raw(float x) {
    float r;
    asm("v_exp_f32 %0, %1" : "=v"(r) : "v"(x));
    return r;
}

// async global->LDS, 16B per lane. LDS dest is wave-uniform base + lane*16.
static __device__ __forceinline__ void gload16(const void* g, void* l) {
    __builtin_amdgcn_global_load_lds(
        (const __attribute__((address_space(1))) void*)g,
        (__attribute__((address_space(3))) void*)l, 16, 0, 0);
}

// swizzled b128 fragment read from a linear [rows][64-short] LDS tile.
static __device__ __forceinline__ s16x8 lds_frag(const short* base, int row, int chunk) {
    return *(const s16x8*)&base[(row << 6) + ((chunk ^ (row & 7)) << 3)];
}

// ---------------- prep kernels ----------------

__global__ __launch_bounds__(256) void cast_f32_bf16(
    const float* __restrict__ in, short* __restrict__ out, int n8)
{
    int i = blockIdx.x * 256 + threadIdx.x;
    if (i >= n8) return;
    float4 a = *(const float4*)&in[i * 8];
    float4 b = *(const float4*)&in[i * 8 + 4];
    s16x8 o = { f2bf(a.x), f2bf(a.y), f2bf(a.z), f2bf(a.w),
                f2bf(b.x), f2bf(b.y), f2bf(b.z), f2bf(b.w) };
    *(s16x8*)&out[i * 8] = o;
}

// src [K][N] f32 row-major  ->  dst [N][K] bf16 row-major
__global__ __launch_bounds__(256) void transpose_cast(
    const float* __restrict__ src, short* __restrict__ dst, int K, int N)
{
    __shared__ short t[64][66];
    int tid = threadIdx.x;
    int n0 = blockIdx.x * 64, k0 = blockIdx.y * 64;
    #pragma unroll
    for (int p = 0; p < 4; ++p) {
        int cid = tid + p * 256;
        int r = cid >> 4, c4 = cid & 15;
        float4 v = *(const float4*)&src[(size_t)(k0 + r) * N + n0 + c4 * 4];
        t[r][c4 * 4 + 0] = f2bf(v.x);
        t[r][c4 * 4 + 1] = f2bf(v.y);
        t[r][c4 * 4 + 2] = f2bf(v.z);
        t[r][c4 * 4 + 3] = f2bf(v.w);
    }
    __syncthreads();
    #pragma unroll
    for (int p = 0; p < 4; ++p) {
        int cid = tid + p * 256;
        int r = cid >> 4, c4 = cid & 15;
        s16x4 ov;
        #pragma unroll
        for (int j = 0; j < 4; ++j) ov[j] = t[c4 * 4 + j][r];
        *(s16x4*)&dst[(size_t)(n0 + r) * K + k0 + c4 * 4] = ov;
    }
}

// ---------------- GEMM: C[M][N] = A[M][1024] * Bt[N][1024]^T (+bias) ----------------
// Counted-vmcnt double-buffer (r16, verified): stage tile k+1 during compute of
// tile k; raw s_barrier + per-wave vmcnt(8).
// MODE 1: q pre-scaled by 1/sqrt(dh)*log2(e); v stored sigma-permuted (g bit-swap)

template<int MODE>
__global__ __launch_bounds__(256) void gemm_bt(
    const short* __restrict__ A, const short* __restrict__ Bt,
    const float* __restrict__ bias, float* __restrict__ out,
    short* __restrict__ qout, short* __restrict__ kout, short* __restrict__ vout)
{
    const int K = 1024;
    __shared__ short As[2][128 * 64];
    __shared__ short Bs[2][128 * 64];
    int tid = threadIdx.x;
    int lane = tid & 63, w = tid >> 6;
    int d = lane & 15, g = lane >> 4;
    int wm = w >> 1, wn = w & 1;

    // XCD-aware bijective swizzle (grid sizes divisible by 8)
    int gx = gridDim.x;
    int lid = blockIdx.y * gx + blockIdx.x;
    int chunk = (gx * gridDim.y) >> 3;
    int sl = (lid & 7) * chunk + (lid >> 3);
    int m0 = (sl / gx) * 128, n0 = (sl % gx) * 128;

    f32x4 acc[4][4];
    #pragma unroll
    for (int i = 0; i < 4; ++i)
        #pragma unroll
        for (int j = 0; j < 4; ++j) acc[i][j] = (f32x4){0.f, 0.f, 0.f, 0.f};

    // staging geometry (loop-invariant)
    int r_ = tid >> 3, c8_ = tid & 7;
    int co_ = (c8_ ^ (r_ & 7)) << 3;

    #define GSTAGE(buf, kt) do { \
        _Pragma("unroll") \
        for (int p = 0; p < 4; ++p) { \
            int rr = p * 32 + r_; \
            int dofs = (p * 256 + (tid & ~63)) * 8; \
            gload16(&A[(size_t)(m0 + rr) * K + (kt) + co_], &As[buf][dofs]); \
            gload16(&Bt[(size_t)(n0 + rr) * K + (kt) + co_], &Bs[buf][dofs]); \
        } \
    } while (0)

    GSTAGE(0, 0);
    int cur = 0;

    #pragma unroll 1
    for (int kt = 0; kt < K; kt += 64) {
        if (kt + 64 < K) {
            GSTAGE(cur ^ 1, kt + 64);
            asm volatile("s_waitcnt vmcnt(8)" ::: "memory");  // tile kt ready; kt+64 in flight
        } else {
            asm volatile("s_waitcnt vmcnt(0)" ::: "memory");
        }
        __builtin_amdgcn_s_barrier();

        const short* Ab = As[cur];
        const short* Bb = Bs[cur];
        #pragma unroll
        for (int ks = 0; ks < 2; ++ks) {
            s16x8 af[4], bf[4];
            #pragma unroll
            for (int i = 0; i < 4; ++i) {
                af[i] = lds_frag(Ab, wm * 64 + i * 16 + d, ks * 4 + g);
                bf[i] = lds_frag(Bb, wn * 64 + i * 16 + d, ks * 4 + g);
            }
            #pragma unroll
            for (int mi = 0; mi < 4; ++mi)
                #pragma unroll
                for (int ni = 0; ni < 4; ++ni)
                    acc[mi][ni] = __builtin_amdgcn_mfma_f32_16x16x32_bf16(
                        af[mi], bf[ni], acc[mi][ni], 0, 0, 0);
        }

        __builtin_amdgcn_s_barrier();
        cur ^= 1;
    }
    #undef GSTAGE

    #pragma unroll
    for (int mi = 0; mi < 4; ++mi)
        #pragma unroll
        for (int ni = 0; ni < 4; ++ni) {
            int gn = n0 + wn * 64 + ni * 16 + d;
            float bv = bias[gn];
            int gm0 = m0 + wm * 64 + mi * 16 + g * 4;
            if (MODE == 0) {
                #pragma unroll
                for (int r = 0; r < 4; ++r)
                    out[(size_t)(gm0 + r) * 1024 + gn] = acc[mi][ni][r] + bv;
            } else {
                int which = gn >> 10, cc = gn & 1023;
                int h = cc >> 6, dh = cc & 63;
                int b = gm0 >> 11;
                if (which == 2) {
                    // sigma-permute t within its 16-group: swap bits of g
                    int g2 = ((g & 1) << 1) | (g >> 1);
                    int t0v = (gm0 & 2047) - g * 4 + g2 * 4;
                    s16x4 pv;
                    #pragma unroll
                    for (int r = 0; r < 4; ++r) pv[r] = f2bf(acc[mi][ni][r] + bv);
                    *(s16x4*)&vout[((size_t)(b * 16 + h) * 64 + dh) * 2048 + t0v] = pv;
                } else if (which == 1) {
                    int t0 = gm0 & 2047;
                    #pragma unroll
                    for (int r = 0; r < 4; ++r)
                        kout[((size_t)(b * 16 + h) * 2048 + (t0 + r)) * 64 + dh] =
                            f2bf(acc[mi][ni][r] + bv);
                } else {
                    int t0 = gm0 & 2047;
                    const float SC2 = 0.125f * 1.44269504089f;  // 1/sqrt(64)*log2(e)
                    #pragma unroll
                    for (int r = 0; r < 4; ++r)
                        qout[((size_t)(b * 16 + h) * 2048 + (t0 + r)) * 64 + dh] =
                            f2bf((acc[mi][ni][r] + bv) * SC2);
                }
            }
        }
}

// ---------------- flash attention ----------------
// r16 base (best measured) + cross-tile pipeline (T15-style): packed P of tile
// t-1 is held in registers; each iteration runs PV(t-1) [V resident in the
// inactive buffer, read BEFORE the stage barrier] -> barrier -> STAGE(t+1) +
// vmcnt(4) -> barrier -> QK(t) -> exp/pack(t). PV and QK are now independent
// back-to-back MFMA; the exp chain trails and overlaps other waves' MFMA.

__global__ __launch_bounds__(256, 4) void attn_fwd(
    const short* __restrict__ q, const short* __restrict__ kk,
    const short* __restrict__ vt, short* __restrict__ y)
{
    __shared__ short Ks[2][64 * 64];
    __shared__ short Vs[2][64 * 64];
    int tid = threadIdx.x, w = tid >> 6;
    int lane = tid & 63;
    int q5 = lane & 31, h5 = lane >> 5;
    int bid = blockIdx.x;
    int idx = bid >> 3;
    int qt = 15 - (idx >> 3);
    int bh = ((idx & 7) << 3) | (bid & 7);
    int b = bh >> 4, hh = bh & 15;
    const size_t hb = (size_t)bh * 2048 * 64;
    int nt = 2 * qt + 2;                 // # of 64-wide K tiles (>=2)
    int qrow = qt * 128 + w * 32;
    int qg = qrow + q5;

    s16x8 qf[4];
    #pragma unroll
    for (int s = 0; s < 4; ++s)
        qf[s] = *(const s16x8*)&q[hb + (size_t)qg * 64 + 16 * s + 8 * h5];

    f32x16 oA, oB;
    #pragma unroll
    for (int i = 0; i < 16; ++i) { oA[i] = 0.f; oB[i] = 0.f; }
    float l = 0.f;

    unsigned wdA[8], wdB[8];             // packed P of previous tile
    bool haveP = false;

    #define STAGE(buf, kt2) do { \
        _Pragma("unroll") \
        for (int p = 0; p < 2; ++p) { \
            int cid = p * 256 + tid; \
            int r__ = cid >> 3, c8__ = cid & 7; \
            int co__ = (c8__ ^ (r__ & 7)) << 3; \
            int dofs__ = (p * 256 + (tid & ~63)) * 8; \
            gload16(&kk[hb + (size_t)((kt2) * 64 + r__) * 64 + co__], &Ks[buf][dofs__]); \
            gload16(&vt[hb + (size_t)r__ * 2048 + (kt2) * 64 + co__], &Vs[buf][dofs__]); \
        } \
    } while (0)

    #define PV_STEP(Vb) do { \
        _Pragma("unroll") \
        for (int kc = 0; kc < 4; ++kc) { \
            const unsigned* wsrc = (kc < 2) ? wdA : wdB; \
            int o4 = (kc & 1) << 2; \
            u32x4 pw = {wsrc[o4], wsrc[o4 + 1], wsrc[o4 + 2], wsrc[o4 + 3]}; \
            s16x8 pb = __builtin_bit_cast(s16x8, pw); \
            oA = __builtin_amdgcn_mfma_f32_32x32x16_bf16( \
                lds_frag((Vb), q5, 2 * kc + h5), pb, oA, 0, 0, 0); \
            oB = __builtin_amdgcn_mfma_f32_32x32x16_bf16( \
                lds_frag((Vb), 32 + q5, 2 * kc + h5), pb, oB, 0, 0, 0); \
        } \
    } while (0)

    STAGE(0, 0);
    int cur = 0;

    #pragma unroll 1
    for (int t = 0; t < nt; ++t) {
        // PV for tile t-1 (V resident in the inactive buffer; register P)
        if (haveP) {
            PV_STEP(Vs[cur ^ 1]);
        }
        __builtin_amdgcn_s_barrier();    // all waves done reading Vs[cur^1]

        if (t + 1 < nt) {
            STAGE(cur ^ 1, t + 1);
            asm volatile("s_waitcnt vmcnt(4)" ::: "memory");  // tile t complete
        } else {
            asm volatile("s_waitcnt vmcnt(0)" ::: "memory");
        }
        __builtin_amdgcn_s_barrier();    // tile t visible to all waves

        if (t * 64 <= qrow + 31) {
            const short* Kb = Ks[cur];

            f32x16 sA, sB;
            #pragma unroll
            for (int i2 = 0; i2 < 16; ++i2) { sA[i2] = 0.f; sB[i2] = 0.f; }
            #pragma unroll
            for (int s = 0; s < 4; ++s) {
                sA = __builtin_amdgcn_mfma_f32_32x32x16_bf16(
                    lds_frag(Kb, q5, 2 * s + h5), qf[s], sA, 0, 0, 0);
                sB = __builtin_amdgcn_mfma_f32_32x32x16_bf16(
                    lds_frag(Kb, 32 + q5, 2 * s + h5), qf[s], sB, 0, 0, 0);
            }

            float eA[16], eB[16];
            float S = 0.f;
            if (t * 64 + 63 > qrow) {
                #pragma unroll
                for (int rg = 0; rg < 16; ++rg) {
                    int kg = t * 64 + (rg & 3) + 8 * (rg >> 2) + 4 * h5;
                    float a = exp2_raw(sA[rg]); if (kg > qg) a = 0.f;
                    float c = exp2_raw(sB[rg]); if (kg + 32 > qg) c = 0.f;
                    eA[rg] = a; eB[rg] = c; S += a + c;
                }
            } else {
                #pragma unroll
                for (int rg = 0; rg < 16; ++rg) {
                    float a = exp2_raw(sA[rg]);
                    float c = exp2_raw(sB[rg]);
                    eA[rg] = a; eB[rg] = c; S += a + c;
                }
            }
            l += S;

            #pragma unroll
            for (int m = 0; m < 4; ++m) {
                wdA[2 * m]     = pack2(eA[4 * m],     eA[4 * m + 1]);
                wdA[2 * m + 1] = pack2(eA[4 * m + 2], eA[4 * m + 3]);
                wdB[2 * m]     = pack2(eB[4 * m],     eB[4 * m + 1]);
                wdB[2 * m + 1] = pack2(eB[4 * m + 2], eB[4 * m + 3]);
            }
            haveP = true;
        } else {
            haveP = false;
        }

        cur ^= 1;
    }

    // drain the last tile's PV
    if (haveP) {
        PV_STEP(Vs[cur ^ 1]);
    }

    l += __shfl_xor(l, 32);
    float rl = 1.0f / l;

    short* yp = &y[(size_t)(b * 2048 + qg) * 1024 + hh * 64];
    #pragma unroll
    for (int m = 0; m < 4; ++m) {
        s16x4 v0, v1;
        #pragma unroll
        for (int i = 0; i < 4; ++i) {
            v0[i] = f2bf(oA[4 * m + i] * rl);
            v1[i] = f2bf(oB[4 * m + i] * rl);
        }
        *(s16x4*)&yp[8 * m + 4 * h5] = v0;
        *(s16x4*)&yp[32 + 8 * m + 4 * h5] = v1;
    }
    #undef STAGE
    #undef PV_STEP
}

// ---------------- launch ----------------

extern "C" void kernel_launch(void* const* d_in, const int* in_sizes, int n_in,
                              void* d_out, int out_size, void* d_ws, size_t ws_size,
                              hipStream_t stream)
{
    const float* x    = (const float*)d_in[0];
    const float* Wqkv = (const float*)d_in[1];
    const float* bqkv = (const float*)d_in[2];
    const float* Wout = (const float*)d_in[3];
    const float* bout = (const float*)d_in[4];
    float* out = (float*)d_out;

    char* ws = (char*)d_ws;
    short* xbf   = (short*)ws;  ws += (size_t)M_ * C_ * 2;
    short* wqkvT = (short*)ws;  ws += (size_t)N3_ * C_ * 2;
    short* woutT = (short*)ws;  ws += (size_t)C_ * C_ * 2;
    short* qb    = (short*)ws;  ws += (size_t)M_ * C_ * 2;
    short* kb    = (short*)ws;  ws += (size_t)M_ * C_ * 2;
    short* vtb   = (short*)ws;  ws += (size_t)M_ * C_ * 2;   // V^T, sigma-permuted
    short* yb    = (short*)ws;  ws += (size_t)M_ * C_ * 2;

    cast_f32_bf16<<<(M_ * C_ / 8 + 255) / 256, 256, 0, stream>>>(x, xbf, M_ * C_ / 8);
    transpose_cast<<<dim3(N3_ / 64, C_ / 64), 256, 0, stream>>>(Wqkv, wqkvT, C_, N3_);
    transpose_cast<<<dim3(C_ / 64, C_ / 64), 256, 0, stream>>>(Wout, woutT, C_, C_);

    gemm_bt<1><<<dim3(N3_ / 128, M_ / 128), 256, 0, stream>>>(
        xbf, wqkvT, bqkv, nullptr, qb, kb, vtb);

    attn_fwd<<<dim3((T_ / 128) * B_ * H_), 256, 0, stream>>>(qb, kb, vtb, yb);

    gemm_bt<0><<<dim3(C_ / 128, M_ / 128), 256, 0, stream>>>(
        yb, woutT, bout, out, nullptr, nullptr, nullptr);
}

// Round 21
// 170.747 us; speedup vs baseline: 1.1683x; 1.0045x over previous
//
#include <hip/hip_runtime.h>
#include <hip/hip_bf16.h>

typedef float f32x4 __attribute__((ext_vector_type(4)));
typedef float f32x16 __attribute__((ext_vector_type(16)));
typedef short s16x8 __attribute__((ext_vector_type(8)));
typedef short s16x4 __attribute__((ext_vector_type(4)));
typedef unsigned int u32x4 __attribute__((ext_vector_type(4)));

#define B_ 4
#define T_ 2048
#define C_ 1024
#define H_ 16
#define DH_ 64
#define M_ (B_*T_)      // 8192
#define N3_ (3*C_)      // 3072

static __device__ __forceinline__ short f2bf(float f) {
    __hip_bfloat16 h = __float2bfloat16(f);
    return *reinterpret_cast<short*>(&h);
}

// hardware packed f32x2 -> bf16x2 (lo in low half), RNE
static __device__ __forceinline__ unsigned pack2(float lo, float hi) {
    unsigned r;
    asm("v_cvt_pk_bf16_f32 %0, %1, %2" : "=v"(r) : "v"(lo), "v"(hi));
    return r;
}

// raw v_exp_f32: D = 2^S0 (scores bounded, pre-scaled to log2 domain)
static __device__ __forceinline__ float exp2_raw(float x) {
    float r;
    asm("v_exp_f32 %0, %1" : "=v"(r) : "v"(x));
    return r;
}

// async global->LDS, 16B per lane. LDS dest is wave-uniform base + lane*16.
static __device__ __forceinline__ void gload16(const void* g, void* l) {
    __builtin_amdgcn_global_load_lds(
        (const __attribute__((address_space(1))) void*)g,
        (__attribute__((address_space(3))) void*)l, 16, 0, 0);
}

// swizzled b128 fragment read from a linear [rows][64-short] LDS tile.
static __device__ __forceinline__ s16x8 lds_frag(const short* base, int row, int chunk) {
    return *(const s16x8*)&base[(row << 6) + ((chunk ^ (row & 7)) << 3)];
}

// ---------------- prep kernels ----------------

__global__ __launch_bounds__(256) void cast_f32_bf16(
    const float* __restrict__ in, short* __restrict__ out, int n8)
{
    int i = blockIdx.x * 256 + threadIdx.x;
    if (i >= n8) return;
    float4 a = *(const float4*)&in[i * 8];
    float4 b = *(const float4*)&in[i * 8 + 4];
    s16x8 o = { f2bf(a.x), f2bf(a.y), f2bf(a.z), f2bf(a.w),
                f2bf(b.x), f2bf(b.y), f2bf(b.z), f2bf(b.w) };
    *(s16x8*)&out[i * 8] = o;
}

// src [K][N] f32 row-major  ->  dst [N][K] bf16 row-major
__global__ __launch_bounds__(256) void transpose_cast(
    const float* __restrict__ src, short* __restrict__ dst, int K, int N)
{
    __shared__ short t[64][66];
    int tid = threadIdx.x;
    int n0 = blockIdx.x * 64, k0 = blockIdx.y * 64;
    #pragma unroll
    for (int p = 0; p < 4; ++p) {
        int cid = tid + p * 256;
        int r = cid >> 4, c4 = cid & 15;
        float4 v = *(const float4*)&src[(size_t)(k0 + r) * N + n0 + c4 * 4];
        t[r][c4 * 4 + 0] = f2bf(v.x);
        t[r][c4 * 4 + 1] = f2bf(v.y);
        t[r][c4 * 4 + 2] = f2bf(v.z);
        t[r][c4 * 4 + 3] = f2bf(v.w);
    }
    __syncthreads();
    #pragma unroll
    for (int p = 0; p < 4; ++p) {
        int cid = tid + p * 256;
        int r = cid >> 4, c4 = cid & 15;
        s16x4 ov;
        #pragma unroll
        for (int j = 0; j < 4; ++j) ov[j] = t[c4 * 4 + j][r];
        *(s16x4*)&dst[(size_t)(n0 + r) * K + k0 + c4 * 4] = ov;
    }
}

// ---------------- GEMM: C[M][N] = A[M][1024] * Bt[N][1024]^T (+bias) ----------------
// Counted-vmcnt double-buffer: stage tile k+1 during compute of tile k; raw
// s_barrier + per-wave vmcnt(8) -- no vmcnt(0) drain in the main loop.
// MODE 1: q pre-scaled by 1/sqrt(dh)*log2(e); v stored sigma-permuted (g bit-swap)

template<int MODE>
__global__ __launch_bounds__(256) void gemm_bt(
    const short* __restrict__ A, const short* __restrict__ Bt,
    const float* __restrict__ bias, float* __restrict__ out,
    short* __restrict__ qout, short* __restrict__ kout, short* __restrict__ vout)
{
    const int K = 1024;
    __shared__ short As[2][128 * 64];
    __shared__ short Bs[2][128 * 64];
    int tid = threadIdx.x;
    int lane = tid & 63, w = tid >> 6;
    int d = lane & 15, g = lane >> 4;
    int wm = w >> 1, wn = w & 1;

    // XCD-aware bijective swizzle (grid sizes divisible by 8)
    int gx = gridDim.x;
    int lid = blockIdx.y * gx + blockIdx.x;
    int chunk = (gx * gridDim.y) >> 3;
    int sl = (lid & 7) * chunk + (lid >> 3);
    int m0 = (sl / gx) * 128, n0 = (sl % gx) * 128;

    f32x4 acc[4][4];
    #pragma unroll
    for (int i = 0; i < 4; ++i)
        #pragma unroll
        for (int j = 0; j < 4; ++j) acc[i][j] = (f32x4){0.f, 0.f, 0.f, 0.f};

    // staging geometry (loop-invariant)
    int r_ = tid >> 3, c8_ = tid & 7;
    int co_ = (c8_ ^ (r_ & 7)) << 3;

    #define GSTAGE(buf, kt) do { \
        _Pragma("unroll") \
        for (int p = 0; p < 4; ++p) { \
            int rr = p * 32 + r_; \
            int dofs = (p * 256 + (tid & ~63)) * 8; \
            gload16(&A[(size_t)(m0 + rr) * K + (kt) + co_], &As[buf][dofs]); \
            gload16(&Bt[(size_t)(n0 + rr) * K + (kt) + co_], &Bs[buf][dofs]); \
        } \
    } while (0)

    GSTAGE(0, 0);
    int cur = 0;

    #pragma unroll 1
    for (int kt = 0; kt < K; kt += 64) {
        if (kt + 64 < K) {
            GSTAGE(cur ^ 1, kt + 64);
            asm volatile("s_waitcnt vmcnt(8)" ::: "memory");  // tile kt ready; kt+64 in flight
        } else {
            asm volatile("s_waitcnt vmcnt(0)" ::: "memory");
        }
        __builtin_amdgcn_s_barrier();

        const short* Ab = As[cur];
        const short* Bb = Bs[cur];
        #pragma unroll
        for (int ks = 0; ks < 2; ++ks) {
            s16x8 af[4], bf[4];
            #pragma unroll
            for (int i = 0; i < 4; ++i) {
                af[i] = lds_frag(Ab, wm * 64 + i * 16 + d, ks * 4 + g);
                bf[i] = lds_frag(Bb, wn * 64 + i * 16 + d, ks * 4 + g);
            }
            #pragma unroll
            for (int mi = 0; mi < 4; ++mi)
                #pragma unroll
                for (int ni = 0; ni < 4; ++ni)
                    acc[mi][ni] = __builtin_amdgcn_mfma_f32_16x16x32_bf16(
                        af[mi], bf[ni], acc[mi][ni], 0, 0, 0);
        }

        __builtin_amdgcn_s_barrier();
        cur ^= 1;
    }
    #undef GSTAGE

    #pragma unroll
    for (int mi = 0; mi < 4; ++mi)
        #pragma unroll
        for (int ni = 0; ni < 4; ++ni) {
            int gn = n0 + wn * 64 + ni * 16 + d;
            float bv = bias[gn];
            int gm0 = m0 + wm * 64 + mi * 16 + g * 4;
            if (MODE == 0) {
                #pragma unroll
                for (int r = 0; r < 4; ++r)
                    out[(size_t)(gm0 + r) * 1024 + gn] = acc[mi][ni][r] + bv;
            } else {
                int which = gn >> 10, cc = gn & 1023;
                int h = cc >> 6, dh = cc & 63;
                int b = gm0 >> 11;
                if (which == 2) {
                    // sigma-permute t within its 16-group: swap bits of g
                    int g2 = ((g & 1) << 1) | (g >> 1);
                    int t0v = (gm0 & 2047) - g * 4 + g2 * 4;
                    s16x4 pv;
                    #pragma unroll
                    for (int r = 0; r < 4; ++r) pv[r] = f2bf(acc[mi][ni][r] + bv);
                    *(s16x4*)&vout[((size_t)(b * 16 + h) * 64 + dh) * 2048 + t0v] = pv;
                } else if (which == 1) {
                    int t0 = gm0 & 2047;
                    #pragma unroll
                    for (int r = 0; r < 4; ++r)
                        kout[((size_t)(b * 16 + h) * 2048 + (t0 + r)) * 64 + dh] =
                            f2bf(acc[mi][ni][r] + bv);
                } else {
                    int t0 = gm0 & 2047;
                    const float SC2 = 0.125f * 1.44269504089f;  // 1/sqrt(64)*log2(e)
                    #pragma unroll
                    for (int r = 0; r < 4; ++r)
                        qout[((size_t)(b * 16 + h) * 2048 + (t0 + r)) * 64 + dh] =
                            f2bf((acc[mi][ni][r] + bv) * SC2);
                }
            }
        }
}

// ---------------- flash attention ----------------
// Best measured (r16): QBLK=128, 4 waves x 32 q-rows, 32x32x16, swapped QK^T,
// sigma-permuted PV, double-buffered counted-vmcnt, 1024 blocks qt-descending,
// raw v_exp_f32 softmax (no-max: scores analytically bounded, log2 domain).

__global__ __launch_bounds__(256, 4) void attn_fwd(
    const short* __restrict__ q, const short* __restrict__ kk,
    const short* __restrict__ vt, short* __restrict__ y)
{
    __shared__ short Ks[2][64 * 64];
    __shared__ short Vs[2][64 * 64];
    int tid = threadIdx.x, w = tid >> 6;
    int lane = tid & 63;
    int q5 = lane & 31, h5 = lane >> 5;
    int bid = blockIdx.x;
    int idx = bid >> 3;
    int qt = 15 - (idx >> 3);
    int bh = ((idx & 7) << 3) | (bid & 7);
    int b = bh >> 4, hh = bh & 15;
    const size_t hb = (size_t)bh * 2048 * 64;
    int nt = 2 * qt + 2;                 // # of 64-wide K tiles (>=2)
    int qrow = qt * 128 + w * 32;
    int qg = qrow + q5;

    s16x8 qf[4];
    #pragma unroll
    for (int s = 0; s < 4; ++s)
        qf[s] = *(const s16x8*)&q[hb + (size_t)qg * 64 + 16 * s + 8 * h5];

    f32x16 oA, oB;
    #pragma unroll
    for (int i = 0; i < 16; ++i) { oA[i] = 0.f; oB[i] = 0.f; }
    float l = 0.f;

    #define STAGE(buf, kt2) do { \
        _Pragma("unroll") \
        for (int p = 0; p < 2; ++p) { \
            int cid = p * 256 + tid; \
            int r__ = cid >> 3, c8__ = cid & 7; \
            int co__ = (c8__ ^ (r__ & 7)) << 3; \
            int dofs__ = (p * 256 + (tid & ~63)) * 8; \
            gload16(&kk[hb + (size_t)((kt2) * 64 + r__) * 64 + co__], &Ks[buf][dofs__]); \
            gload16(&vt[hb + (size_t)r__ * 2048 + (kt2) * 64 + co__], &Vs[buf][dofs__]); \
        } \
    } while (0)

    STAGE(0, 0);
    int cur = 0;

    #pragma unroll 1
    for (int t = 0; t < nt; ++t) {
        if (t + 1 < nt) {
            STAGE(cur ^ 1, t + 1);
            asm volatile("s_waitcnt vmcnt(4)" ::: "memory");  // tile t ready; t+1 in flight
        } else {
            asm volatile("s_waitcnt vmcnt(0)" ::: "memory");
        }
        __builtin_amdgcn_s_barrier();

        if (t * 64 <= qrow + 31) {
            const short* Kb = Ks[cur];
            const short* Vb = Vs[cur];

            f32x16 sA, sB;
            #pragma unroll
            for (int i2 = 0; i2 < 16; ++i2) { sA[i2] = 0.f; sB[i2] = 0.f; }
            #pragma unroll
            for (int s = 0; s < 4; ++s) {
                sA = __builtin_amdgcn_mfma_f32_32x32x16_bf16(
                    lds_frag(Kb, q5, 2 * s + h5), qf[s], sA, 0, 0, 0);
                sB = __builtin_amdgcn_mfma_f32_32x32x16_bf16(
                    lds_frag(Kb, 32 + q5, 2 * s + h5), qf[s], sB, 0, 0, 0);
            }

            float eA[16], eB[16];
            float S = 0.f;
            if (t * 64 + 63 > qrow) {
                #pragma unroll
                for (int rg = 0; rg < 16; ++rg) {
                    int kg = t * 64 + (rg & 3) + 8 * (rg >> 2) + 4 * h5;
                    float a = exp2_raw(sA[rg]); if (kg > qg) a = 0.f;
                    float c = exp2_raw(sB[rg]); if (kg + 32 > qg) c = 0.f;
                    eA[rg] = a; eB[rg] = c; S += a + c;
                }
            } else {
                #pragma unroll
                for (int rg = 0; rg < 16; ++rg) {
                    float a = exp2_raw(sA[rg]);
                    float c = exp2_raw(sB[rg]);
                    eA[rg] = a; eB[rg] = c; S += a + c;
                }
            }
            l += S;

            unsigned wdA[8], wdB[8];
            #pragma unroll
            for (int m = 0; m < 4; ++m) {
                wdA[2 * m]     = pack2(eA[4 * m],     eA[4 * m + 1]);
                wdA[2 * m + 1] = pack2(eA[4 * m + 2], eA[4 * m + 3]);
                wdB[2 * m]     = pack2(eB[4 * m],     eB[4 * m + 1]);
                wdB[2 * m + 1] = pack2(eB[4 * m + 2], eB[4 * m + 3]);
            }

            #pragma unroll
            for (int kc = 0; kc < 4; ++kc) {
                const unsigned* wsrc = (kc < 2) ? wdA : wdB;
                int o4 = (kc & 1) << 2;
                u32x4 pw = {wsrc[o4], wsrc[o4 + 1], wsrc[o4 + 2], wsrc[o4 + 3]};
                s16x8 pb = __builtin_bit_cast(s16x8, pw);
                oA = __builtin_amdgcn_mfma_f32_32x32x16_bf16(
                    lds_frag(Vb, q5, 2 * kc + h5), pb, oA, 0, 0, 0);
                oB = __builtin_amdgcn_mfma_f32_32x32x16_bf16(
                    lds_frag(Vb, 32 + q5, 2 * kc + h5), pb, oB, 0, 0, 0);
            }
        }

        __builtin_amdgcn_s_barrier();
        cur ^= 1;
    }

    l += __shfl_xor(l, 32);
    float rl = 1.0f / l;

    short* yp = &y[(size_t)(b * 2048 + qg) * 1024 + hh * 64];
    #pragma unroll
    for (int m = 0; m < 4; ++m) {
        s16x4 v0, v1;
        #pragma unroll
        for (int i = 0; i < 4; ++i) {
            v0[i] = f2bf(oA[4 * m + i] * rl);
            v1[i] = f2bf(oB[4 * m + i] * rl);
        }
        *(s16x4*)&yp[8 * m + 4 * h5] = v0;
        *(s16x4*)&yp[32 + 8 * m + 4 * h5] = v1;
    }
    #undef STAGE
}

// ---------------- launch ----------------

extern "C" void kernel_launch(void* const* d_in, const int* in_sizes, int n_in,
                              void* d_out, int out_size, void* d_ws, size_t ws_size,
                              hipStream_t stream)
{
    const float* x    = (const float*)d_in[0];
    const float* Wqkv = (const float*)d_in[1];
    const float* bqkv = (const float*)d_in[2];
    const float* Wout = (const float*)d_in[3];
    const float* bout = (const float*)d_in[4];
    float* out = (float*)d_out;

    char* ws = (char*)d_ws;
    short* xbf   = (short*)ws;  ws += (size_t)M_ * C_ * 2;
    short* wqkvT = (short*)ws;  ws += (size_t)N3_ * C_ * 2;
    short* woutT = (short*)ws;  ws += (size_t)C_ * C_ * 2;
    short* qb    = (short*)ws;  ws += (size_t)M_ * C_ * 2;
    short* kb    = (short*)ws;  ws += (size_t)M_ * C_ * 2;
    short* vtb   = (short*)ws;  ws += (size_t)M_ * C_ * 2;   // V^T, sigma-permuted
    short* yb    = (short*)ws;  ws += (size_t)M_ * C_ * 2;

    cast_f32_bf16<<<(M_ * C_ / 8 + 255) / 256, 256, 0, stream>>>(x, xbf, M_ * C_ / 8);
    transpose_cast<<<dim3(N3_ / 64, C_ / 64), 256, 0, stream>>>(Wqkv, wqkvT, C_, N3_);
    transpose_cast<<<dim3(C_ / 64, C_ / 64), 256, 0, stream>>>(Wout, woutT, C_, C_);

    gemm_bt<1><<<dim3(N3_ / 128, M_ / 128), 256, 0, stream>>>(
        xbf, wqkvT, bqkv, nullptr, qb, kb, vtb);

    attn_fwd<<<dim3((T_ / 128) * B_ * H_), 256, 0, stream>>>(qb, kb, vtb, yb);

    gemm_bt<0><<<dim3(C_ / 128, M_ / 128), 256, 0, stream>>>(
        yb, woutT, bout, out, nullptr, nullptr, nullptr);
}